// Round 1
// baseline (1210.321 us; speedup 1.0000x reference)
//
#include <hip/hip_runtime.h>

#define L_RES 2000
#define DF 54
#define WIN 7

// ---------------- Kernel 1: f = beft @ W_bert + b  (L,1024)@(1024,54) ----------------
__global__ __launch_bounds__(256) void bert_lin(const float* __restrict__ beft,
                                                const float* __restrict__ Wb,
                                                const float* __restrict__ bb,
                                                float* __restrict__ f) {
    int l = blockIdx.x;
    __shared__ float row[1024];
    __shared__ float part[4][DF];
    int t = threadIdx.x;
    for (int k = t; k < 1024; k += 256) row[k] = beft[l * 1024 + k];
    __syncthreads();
    if (t < 216) {
        int n = t % DF, q = t / DF;
        float s = 0.f;
        #pragma unroll 8
        for (int k = q * 256; k < q * 256 + 256; ++k) s = fmaf(row[k], Wb[k * DF + n], s);
        part[q][n] = s;
    }
    __syncthreads();
    if (t < DF) f[l * DF + t] = part[0][t] + part[1][t] + part[2][t] + part[3][t] + bb[t];
}

// ---------------- Kernel 2: window gather + attn x2 + concat ----------------
__device__ __forceinline__ void attn_layer(const float (*in)[DF], float (*out)[DF],
                                           float (*s)[WIN][WIN],
                                           const float* __restrict__ g,
                                           const float* __restrict__ b,
                                           float* mm, float* vv, int t) {
    // s[h][q][k] = sum_d in[q][h*18+d]*in[k][h*18+d]
    for (int idx = t; idx < 3 * WIN * WIN; idx += 64) {
        int h = idx / 49, r = idx % 49, q = r / WIN, k = r % WIN;
        float sum = 0.f;
        #pragma unroll
        for (int d = 0; d < 18; ++d) sum = fmaf(in[q][h * 18 + d], in[k][h * 18 + d], sum);
        s[h][q][k] = sum;
    }
    __syncthreads();
    // softmax over k
    for (int idx = t; idx < 3 * WIN; idx += 64) {
        int h = idx / WIN, q = idx % WIN;
        float mx = s[h][q][0];
        #pragma unroll
        for (int k = 1; k < WIN; ++k) mx = fmaxf(mx, s[h][q][k]);
        float e[WIN], sum = 0.f;
        #pragma unroll
        for (int k = 0; k < WIN; ++k) { e[k] = expf(s[h][q][k] - mx); sum += e[k]; }
        float inv = 1.f / sum;
        #pragma unroll
        for (int k = 0; k < WIN; ++k) s[h][q][k] = e[k] * inv;
    }
    __syncthreads();
    // o[q][c] = sum_k p[h][q][k] * in[k][c],  h = c/18
    for (int idx = t; idx < WIN * DF; idx += 64) {
        int q = idx / DF, c = idx % DF, h = c / 18;
        float sum = 0.f;
        #pragma unroll
        for (int k = 0; k < WIN; ++k) sum = fmaf(s[h][q][k], in[k][c], sum);
        out[q][c] = sum;
    }
    __syncthreads();
    // layernorm stats per q
    for (int q = t; q < WIN; q += 64) {
        float m = 0.f;
        for (int c = 0; c < DF; ++c) m += out[q][c];
        m *= (1.f / DF);
        float v = 0.f;
        for (int c = 0; c < DF; ++c) { float d0 = out[q][c] - m; v = fmaf(d0, d0, v); }
        v *= (1.f / DF);
        mm[q] = m; vv[q] = rsqrtf(v + 1e-5f);
    }
    __syncthreads();
    for (int idx = t; idx < WIN * DF; idx += 64) {
        int q = idx / DF, c = idx % DF;
        out[q][c] = (out[q][c] - mm[q]) * vv[q] * g[c] + b[c];
    }
    __syncthreads();
}

__global__ __launch_bounds__(64) void window_attn(const float* __restrict__ f,
                                                  const float* __restrict__ g1,
                                                  const float* __restrict__ b1,
                                                  const float* __restrict__ g2,
                                                  const float* __restrict__ b2,
                                                  float* __restrict__ cat) {
    int l = blockIdx.x;
    int t = threadIdx.x;
    __shared__ float w[WIN][DF], o1[WIN][DF], o2[WIN][DF];
    __shared__ float s[3][WIN][WIN];
    __shared__ float mm[WIN], vv[WIN];
    bool boundary = (l <= WIN) || (l + WIN >= L_RES);
    for (int idx = t; idx < WIN * DF; idx += 64) {
        int j = idx / DF, d = idx % DF;
        w[j][d] = boundary ? (j == 0 ? f[l * DF + d] : 0.f)
                           : f[(l - 4 + j) * DF + d];
    }
    __syncthreads();
    attn_layer(w, o1, s, g1, b1, mm, vv, t);
    attn_layer(o1, o2, s, g2, b2, mm, vv, t);
    for (int idx = t; idx < WIN * DF; idx += 64) {
        int j = idx / DF, d = idx % DF;
        cat[l * 756 + j * 108 + d] = w[j][d];
        cat[l * 756 + j * 108 + DF + d] = o2[j][d];
    }
}

// ---------------- Kernel 3: conv branches + maxpool fused into GEMM1 ----------------
// per block: one residue l. pooled feats row (32x972) built 8 channels at a time
// in LDS transposed [972][8]; GEMM accumulate into y1[l][c][n].
__global__ __launch_bounds__(256) void conv_gemm1(
        const float* __restrict__ cat,
        const float* __restrict__ c1w, const float* __restrict__ c1b,
        const float* __restrict__ pa_p,
        const float* __restrict__ c2w, const float* __restrict__ c2b,
        const float* __restrict__ c3w, const float* __restrict__ c3b,
        const float* __restrict__ W1, const float* __restrict__ b1v,
        float* __restrict__ y1) {
    int l = blockIdx.x;
    int t = threadIdx.x;
    __shared__ float catl[WIN][108];
    __shared__ float pt[972][8];
    float pa = pa_p[0];
    for (int idx = t; idx < WIN * 108; idx += 256) catl[idx / 108][idx % 108] = cat[l * 756 + idx];
    __syncthreads();
    for (int cc = 0; cc < 4; ++cc) {
        // ---- conv + act + pool for channels cc*8 .. cc*8+7 ----
        for (int idx = t; idx < 8 * 108; idx += 256) {
            int cl = idx / 108, d = idx % 108, c = cc * 8 + cl;
            float col[WIN];
            #pragma unroll
            for (int h = 0; h < WIN; ++h) col[h] = catl[h][d];
            // branch 1: k=3, pad=1, prelu
            {
                float w0 = c1w[c * 3], w1 = c1w[c * 3 + 1], w2 = c1w[c * 3 + 2], bb = c1b[c];
                float v[WIN];
                #pragma unroll
                for (int h = 0; h < WIN; ++h) {
                    float sum = bb;
                    if (h - 1 >= 0) sum = fmaf(w0, col[h - 1], sum);
                    sum = fmaf(w1, col[h], sum);
                    if (h + 1 <= 6) sum = fmaf(w2, col[h + 1], sum);
                    v[h] = sum >= 0.f ? sum : pa * sum;
                }
                #pragma unroll
                for (int p = 0; p < 5; ++p)
                    pt[p * 108 + d][cl] = fmaxf(fmaxf(v[p], v[p + 1]), v[p + 2]);
            }
            // branch 2: k=5, pad=2, relu
            {
                float wg[5], bb = c2b[c];
                #pragma unroll
                for (int x = 0; x < 5; ++x) wg[x] = c2w[c * 5 + x];
                float v[WIN];
                #pragma unroll
                for (int h = 0; h < WIN; ++h) {
                    float sum = bb;
                    #pragma unroll
                    for (int x = 0; x < 5; ++x) {
                        int hh = h + x - 2;
                        if (hh >= 0 && hh <= 6) sum = fmaf(wg[x], col[hh], sum);
                    }
                    v[h] = fmaxf(sum, 0.f);
                }
                #pragma unroll
                for (int p = 0; p < 3; ++p) {
                    float mx = v[p];
                    #pragma unroll
                    for (int r = 1; r < 5; ++r) mx = fmaxf(mx, v[p + r]);
                    pt[540 + p * 108 + d][cl] = mx;
                }
            }
            // branch 3: k=7, pad=3, relu
            {
                float wg[7], bb = c3b[c];
                #pragma unroll
                for (int x = 0; x < 7; ++x) wg[x] = c3w[c * 7 + x];
                float mx = 0.f;  // relu outputs >= 0
                #pragma unroll
                for (int h = 0; h < WIN; ++h) {
                    float sum = bb;
                    #pragma unroll
                    for (int x = 0; x < 7; ++x) {
                        int hh = h + x - 3;
                        if (hh >= 0 && hh <= 6) sum = fmaf(wg[x], col[hh], sum);
                    }
                    mx = fmaxf(mx, fmaxf(sum, 0.f));
                }
                pt[864 + d][cl] = mx;
            }
        }
        __syncthreads();
        // ---- GEMM: y1[l][cc*8+cl][n] = sum_m pt[m][cl] * W1[m][n] + b1[n] ----
        float acc[8] = {0.f, 0.f, 0.f, 0.f, 0.f, 0.f, 0.f, 0.f};
        int n = t;
        for (int m = 0; m < 972; ++m) {
            float wv = W1[m * 256 + n];
            float4 p0 = *(const float4*)&pt[m][0];
            float4 p1 = *(const float4*)&pt[m][4];
            acc[0] = fmaf(p0.x, wv, acc[0]); acc[1] = fmaf(p0.y, wv, acc[1]);
            acc[2] = fmaf(p0.z, wv, acc[2]); acc[3] = fmaf(p0.w, wv, acc[3]);
            acc[4] = fmaf(p1.x, wv, acc[4]); acc[5] = fmaf(p1.y, wv, acc[5]);
            acc[6] = fmaf(p1.z, wv, acc[6]); acc[7] = fmaf(p1.w, wv, acc[7]);
        }
        float bias = b1v[n];
        #pragma unroll
        for (int cl = 0; cl < 8; ++cl)
            y1[(size_t)l * 8192 + (cc * 8 + cl) * 256 + n] = acc[cl] + bias;
        __syncthreads();
    }
}

// ---------------- Kernel 4: y2 = leaky(y1 @ W2 + b2) ----------------
__global__ __launch_bounds__(256) void gemm2(const float* __restrict__ y1,
                                             const float* __restrict__ W2,
                                             const float* __restrict__ b2v,
                                             float* __restrict__ out) {
    int l0 = blockIdx.x * 8;
    int n = threadIdx.x;
    float acc[8] = {0.f, 0.f, 0.f, 0.f, 0.f, 0.f, 0.f, 0.f};
    const float* yb = y1 + (size_t)l0 * 8192;
    #pragma unroll 4
    for (int k = 0; k < 8192; ++k) {
        float wv = W2[(size_t)k * 256 + n];
        #pragma unroll
        for (int r = 0; r < 8; ++r) acc[r] = fmaf(yb[(size_t)r * 8192 + k], wv, acc[r]);
    }
    float bias = b2v[n];
    #pragma unroll
    for (int r = 0; r < 8; ++r) {
        float v = acc[r] + bias;
        out[(size_t)(l0 + r) * 256 + n] = v >= 0.f ? v : 0.01f * v;
    }
}

extern "C" void kernel_launch(void* const* d_in, const int* in_sizes, int n_in,
                              void* d_out, int out_size, void* d_ws, size_t ws_size,
                              hipStream_t stream) {
    const float* beft = (const float*)d_in[0];
    // d_in[1..3] (pssm/hmm/dssp) unused by the reference forward
    const float* Wb  = (const float*)d_in[4];
    const float* bb  = (const float*)d_in[5];
    const float* g1  = (const float*)d_in[6];
    const float* b1  = (const float*)d_in[7];
    const float* g2  = (const float*)d_in[8];
    const float* b2  = (const float*)d_in[9];
    const float* c1w = (const float*)d_in[10];
    const float* c1b = (const float*)d_in[11];
    const float* pa  = (const float*)d_in[12];
    const float* c2w = (const float*)d_in[13];
    const float* c2b = (const float*)d_in[14];
    const float* c3w = (const float*)d_in[15];
    const float* c3b = (const float*)d_in[16];
    const float* W1  = (const float*)d_in[17];
    const float* b1v = (const float*)d_in[18];
    const float* W2  = (const float*)d_in[19];
    const float* b2v = (const float*)d_in[20];
    float* out = (float*)d_out;
    float* ws  = (float*)d_ws;

    float* f   = ws;                         // 2000*54      = 108000  elems
    float* cat = ws + 131072;                // 2000*756     = 1512000 elems
    float* y1  = ws + 131072 + 1572864;      // 2000*8192    = 16384000 elems
    // total ~72.4 MB of workspace

    bert_lin<<<L_RES, 256, 0, stream>>>(beft, Wb, bb, f);
    window_attn<<<L_RES, 64, 0, stream>>>(f, g1, b1, g2, b2, cat);
    conv_gemm1<<<L_RES, 256, 0, stream>>>(cat, c1w, c1b, pa, c2w, c2b, c3w, c3b,
                                          W1, b1v, y1);
    gemm2<<<L_RES / 8, 256, 0, stream>>>(y1, W2, b2v, out);
}

// Round 2
// 206.589 us; speedup vs baseline: 5.8586x; 5.8586x over previous
//
#include <hip/hip_runtime.h>

#define L_RES 2000
#define DF 54
#define WIN 7

typedef short bf16x8 __attribute__((ext_vector_type(8)));
typedef float f32x4 __attribute__((ext_vector_type(4)));

__device__ __forceinline__ unsigned short f2bf(float f) {
    unsigned int u = __float_as_uint(f);
    unsigned int r = (u + 0x7FFFu + ((u >> 16) & 1u)) >> 16;
    return (unsigned short)r;
}

// ---------------- Kernel 1: f = beft @ W_bert + b  (L,1024)@(1024,54) ----------------
__global__ __launch_bounds__(256) void bert_lin(const float* __restrict__ beft,
                                                const float* __restrict__ Wb,
                                                const float* __restrict__ bb,
                                                float* __restrict__ f) {
    int l = blockIdx.x;
    __shared__ float row[1024];
    __shared__ float part[4][DF];
    int t = threadIdx.x;
    for (int k = t; k < 1024; k += 256) row[k] = beft[l * 1024 + k];
    __syncthreads();
    if (t < 216) {
        int n = t % DF, q = t / DF;
        float s = 0.f;
        #pragma unroll 8
        for (int k = q * 256; k < q * 256 + 256; ++k) s = fmaf(row[k], Wb[k * DF + n], s);
        part[q][n] = s;
    }
    __syncthreads();
    if (t < DF) f[l * DF + t] = part[0][t] + part[1][t] + part[2][t] + part[3][t] + bb[t];
}

// ---------------- Kernel 2: window gather + attn x2 + concat ----------------
__device__ __forceinline__ void attn_layer(const float (*in)[DF], float (*out)[DF],
                                           float (*s)[WIN][WIN],
                                           const float* __restrict__ g,
                                           const float* __restrict__ b,
                                           float* mm, float* vv, int t) {
    for (int idx = t; idx < 3 * WIN * WIN; idx += 64) {
        int h = idx / 49, r = idx % 49, q = r / WIN, k = r % WIN;
        float sum = 0.f;
        #pragma unroll
        for (int d = 0; d < 18; ++d) sum = fmaf(in[q][h * 18 + d], in[k][h * 18 + d], sum);
        s[h][q][k] = sum;
    }
    __syncthreads();
    for (int idx = t; idx < 3 * WIN; idx += 64) {
        int h = idx / WIN, q = idx % WIN;
        float mx = s[h][q][0];
        #pragma unroll
        for (int k = 1; k < WIN; ++k) mx = fmaxf(mx, s[h][q][k]);
        float e[WIN], sum = 0.f;
        #pragma unroll
        for (int k = 0; k < WIN; ++k) { e[k] = expf(s[h][q][k] - mx); sum += e[k]; }
        float inv = 1.f / sum;
        #pragma unroll
        for (int k = 0; k < WIN; ++k) s[h][q][k] = e[k] * inv;
    }
    __syncthreads();
    for (int idx = t; idx < WIN * DF; idx += 64) {
        int q = idx / DF, c = idx % DF, h = c / 18;
        float sum = 0.f;
        #pragma unroll
        for (int k = 0; k < WIN; ++k) sum = fmaf(s[h][q][k], in[k][c], sum);
        out[q][c] = sum;
    }
    __syncthreads();
    for (int q = t; q < WIN; q += 64) {
        float m = 0.f;
        for (int c = 0; c < DF; ++c) m += out[q][c];
        m *= (1.f / DF);
        float v = 0.f;
        for (int c = 0; c < DF; ++c) { float d0 = out[q][c] - m; v = fmaf(d0, d0, v); }
        v *= (1.f / DF);
        mm[q] = m; vv[q] = rsqrtf(v + 1e-5f);
    }
    __syncthreads();
    for (int idx = t; idx < WIN * DF; idx += 64) {
        int q = idx / DF, c = idx % DF;
        out[q][c] = (out[q][c] - mm[q]) * vv[q] * g[c] + b[c];
    }
    __syncthreads();
}

__global__ __launch_bounds__(64) void window_attn(const float* __restrict__ f,
                                                  const float* __restrict__ g1,
                                                  const float* __restrict__ b1,
                                                  const float* __restrict__ g2,
                                                  const float* __restrict__ b2,
                                                  float* __restrict__ cat) {
    int l = blockIdx.x;
    int t = threadIdx.x;
    __shared__ float w[WIN][DF], o1[WIN][DF], o2[WIN][DF];
    __shared__ float s[3][WIN][WIN];
    __shared__ float mm[WIN], vv[WIN];
    bool boundary = (l <= WIN) || (l + WIN >= L_RES);
    for (int idx = t; idx < WIN * DF; idx += 64) {
        int j = idx / DF, d = idx % DF;
        w[j][d] = boundary ? (j == 0 ? f[l * DF + d] : 0.f)
                           : f[(l - 4 + j) * DF + d];
    }
    __syncthreads();
    attn_layer(w, o1, s, g1, b1, mm, vv, t);
    attn_layer(o1, o2, s, g2, b2, mm, vv, t);
    for (int idx = t; idx < WIN * DF; idx += 64) {
        int j = idx / DF, d = idx % DF;
        cat[l * 756 + j * 108 + d] = w[j][d];
        cat[l * 756 + j * 108 + DF + d] = o2[j][d];
    }
}

// ---------------- transpose + f32->bf16: dst[n][m] (Mpad rows padded w/ 0) ----------------
__global__ __launch_bounds__(256) void transpose_to_bf16(const float* __restrict__ src,
                                                         unsigned short* __restrict__ dst,
                                                         int M, int N, int Mpad) {
    __shared__ float tile[32][33];
    int m0 = blockIdx.x * 32, n0 = blockIdx.y * 32;
    int c = threadIdx.x % 32, r0 = threadIdx.x / 32;
    #pragma unroll
    for (int rr = 0; rr < 4; ++rr) {
        int r = r0 + rr * 8, m = m0 + r;
        tile[r][c] = (m < M) ? src[(size_t)m * N + n0 + c] : 0.f;
    }
    __syncthreads();
    #pragma unroll
    for (int rr = 0; rr < 4; ++rr) {
        int r = r0 + rr * 8;
        dst[(size_t)(n0 + r) * Mpad + m0 + c] = f2bf(tile[c][r]);
    }
}

// zero bf16 y1 pad rows 2000..2047 (48*8192 ushorts = 196608 uints)
__global__ __launch_bounds__(256) void zero_pad_rows(unsigned int* __restrict__ p) {
    int i = blockIdx.x * 256 + threadIdx.x;
    if (i < 196608) p[i] = 0u;
}

// ---------------- Kernel 3: conv+pool -> bf16 LDS A[32][1000], MFMA vs W1T ----------------
__global__ __launch_bounds__(256) void conv_mfma1(
        const float* __restrict__ cat,
        const float* __restrict__ c1w, const float* __restrict__ c1b,
        const float* __restrict__ pa_p,
        const float* __restrict__ c2w, const float* __restrict__ c2b,
        const float* __restrict__ c3w, const float* __restrict__ c3b,
        const unsigned short* __restrict__ W1T, const float* __restrict__ b1v,
        unsigned short* __restrict__ y1) {
    int l = blockIdx.x;
    int t = threadIdx.x;
    __shared__ float catl[WIN][108];
    __shared__ unsigned short A[32][1000];   // bf16, row stride 2000 B (16B-aligned)
    float pa = pa_p[0];
    for (int idx = t; idx < WIN * 108; idx += 256) catl[idx / 108][idx % 108] = cat[l * 756 + idx];
    for (int idx = t; idx < 32 * 28; idx += 256) A[idx / 28][972 + idx % 28] = 0;
    __syncthreads();
    for (int idx = t; idx < 32 * 108; idx += 256) {
        int c = idx / 108, d = idx % 108;
        float col[WIN];
        #pragma unroll
        for (int h = 0; h < WIN; ++h) col[h] = catl[h][d];
        // branch 1: k=3, prelu, pool3 -> 5 outputs
        {
            float w0 = c1w[c * 3], w1 = c1w[c * 3 + 1], w2 = c1w[c * 3 + 2], bb = c1b[c];
            float v[WIN];
            #pragma unroll
            for (int h = 0; h < WIN; ++h) {
                float sum = bb;
                if (h - 1 >= 0) sum = fmaf(w0, col[h - 1], sum);
                sum = fmaf(w1, col[h], sum);
                if (h + 1 <= 6) sum = fmaf(w2, col[h + 1], sum);
                v[h] = sum >= 0.f ? sum : pa * sum;
            }
            #pragma unroll
            for (int p = 0; p < 5; ++p)
                A[c][p * 108 + d] = f2bf(fmaxf(fmaxf(v[p], v[p + 1]), v[p + 2]));
        }
        // branch 2: k=5, relu, pool5 -> 3 outputs
        {
            float wg[5], bb = c2b[c];
            #pragma unroll
            for (int x = 0; x < 5; ++x) wg[x] = c2w[c * 5 + x];
            float v[WIN];
            #pragma unroll
            for (int h = 0; h < WIN; ++h) {
                float sum = bb;
                #pragma unroll
                for (int x = 0; x < 5; ++x) {
                    int hh = h + x - 2;
                    if (hh >= 0 && hh <= 6) sum = fmaf(wg[x], col[hh], sum);
                }
                v[h] = fmaxf(sum, 0.f);
            }
            #pragma unroll
            for (int p = 0; p < 3; ++p) {
                float mx = v[p];
                #pragma unroll
                for (int r = 1; r < 5; ++r) mx = fmaxf(mx, v[p + r]);
                A[c][540 + p * 108 + d] = f2bf(mx);
            }
        }
        // branch 3: k=7, relu, pool7 -> 1 output
        {
            float wg[7], bb = c3b[c];
            #pragma unroll
            for (int x = 0; x < 7; ++x) wg[x] = c3w[c * 7 + x];
            float mx = 0.f;
            #pragma unroll
            for (int h = 0; h < WIN; ++h) {
                float sum = bb;
                #pragma unroll
                for (int x = 0; x < 7; ++x) {
                    int hh = h + x - 3;
                    if (hh >= 0 && hh <= 6) sum = fmaf(wg[x], col[hh], sum);
                }
                mx = fmaxf(mx, fmaxf(sum, 0.f));
            }
            A[c][864 + d] = f2bf(mx);
        }
    }
    __syncthreads();
    // ---- MFMA: C[32 x 256] = A[32 x 992] @ W1T^T ----
    int w = t >> 6, lane = t & 63;
    int n0 = w * 64;
    int arow = lane & 15, kgrp = lane >> 4;
    f32x4 acc[2][4];
    #pragma unroll
    for (int mi = 0; mi < 2; ++mi)
        #pragma unroll
        for (int ni = 0; ni < 4; ++ni) acc[mi][ni] = (f32x4)(0.f);
    for (int kk = 0; kk < 31; ++kk) {
        int k0 = kk * 32 + kgrp * 8;
        bf16x8 a0 = *(const bf16x8*)&A[arow][k0];
        bf16x8 a1 = *(const bf16x8*)&A[arow + 16][k0];
        bf16x8 b[4];
        #pragma unroll
        for (int ni = 0; ni < 4; ++ni)
            b[ni] = *(const bf16x8*)&W1T[(size_t)(n0 + ni * 16 + arow) * 992 + k0];
        #pragma unroll
        for (int ni = 0; ni < 4; ++ni) {
            acc[0][ni] = __builtin_amdgcn_mfma_f32_16x16x32_bf16(a0, b[ni], acc[0][ni], 0, 0, 0);
            acc[1][ni] = __builtin_amdgcn_mfma_f32_16x16x32_bf16(a1, b[ni], acc[1][ni], 0, 0, 0);
        }
    }
    #pragma unroll
    for (int ni = 0; ni < 4; ++ni) {
        int n = n0 + ni * 16 + arow;
        float bias = b1v[n];
        #pragma unroll
        for (int mi = 0; mi < 2; ++mi)
            #pragma unroll
            for (int r = 0; r < 4; ++r) {
                int c = mi * 16 + kgrp * 4 + r;
                y1[(size_t)l * 8192 + c * 256 + n] = f2bf(acc[mi][ni][r] + bias);
            }
    }
}

// ---------------- Kernel 4: gemm2 partials: part[s][m][n] = y1[m][ks] @ W2T[n][ks] ----------------
__global__ __launch_bounds__(256) void gemm2_mfma(const unsigned short* __restrict__ y1,
                                                  const unsigned short* __restrict__ W2T,
                                                  float* __restrict__ part) {
    int m0 = blockIdx.x * 32;
    int s = blockIdx.y;
    int t = threadIdx.x, w = t >> 6, lane = t & 63;
    int n0 = w * 64;
    int arow = lane & 15, kgrp = lane >> 4;
    f32x4 acc[2][4];
    #pragma unroll
    for (int mi = 0; mi < 2; ++mi)
        #pragma unroll
        for (int ni = 0; ni < 4; ++ni) acc[mi][ni] = (f32x4)(0.f);
    int kbase = s * 1024;
    for (int kk = 0; kk < 32; ++kk) {
        int k0 = kbase + kk * 32 + kgrp * 8;
        bf16x8 a0 = *(const bf16x8*)&y1[(size_t)(m0 + arow) * 8192 + k0];
        bf16x8 a1 = *(const bf16x8*)&y1[(size_t)(m0 + 16 + arow) * 8192 + k0];
        bf16x8 b[4];
        #pragma unroll
        for (int ni = 0; ni < 4; ++ni)
            b[ni] = *(const bf16x8*)&W2T[(size_t)(n0 + ni * 16 + arow) * 8192 + k0];
        #pragma unroll
        for (int ni = 0; ni < 4; ++ni) {
            acc[0][ni] = __builtin_amdgcn_mfma_f32_16x16x32_bf16(a0, b[ni], acc[0][ni], 0, 0, 0);
            acc[1][ni] = __builtin_amdgcn_mfma_f32_16x16x32_bf16(a1, b[ni], acc[1][ni], 0, 0, 0);
        }
    }
    #pragma unroll
    for (int ni = 0; ni < 4; ++ni) {
        int n = n0 + ni * 16 + arow;
        #pragma unroll
        for (int mi = 0; mi < 2; ++mi)
            #pragma unroll
            for (int r = 0; r < 4; ++r) {
                int row = m0 + mi * 16 + kgrp * 4 + r;
                part[((size_t)s * 2048 + row) * 256 + n] = acc[mi][ni][r];
            }
    }
}

// ---------------- Kernel 5: reduce partials + bias + leaky ----------------
__global__ __launch_bounds__(256) void reduce2(const float* __restrict__ part,
                                               const float* __restrict__ b2v,
                                               float* __restrict__ out) {
    int l = blockIdx.x, n = threadIdx.x;
    float sum = b2v[n];
    #pragma unroll
    for (int s = 0; s < 8; ++s) sum += part[((size_t)s * 2048 + l) * 256 + n];
    out[(size_t)l * 256 + n] = sum >= 0.f ? sum : 0.01f * sum;
}

extern "C" void kernel_launch(void* const* d_in, const int* in_sizes, int n_in,
                              void* d_out, int out_size, void* d_ws, size_t ws_size,
                              hipStream_t stream) {
    const float* beft = (const float*)d_in[0];
    const float* Wb  = (const float*)d_in[4];
    const float* bb  = (const float*)d_in[5];
    const float* g1  = (const float*)d_in[6];
    const float* b1  = (const float*)d_in[7];
    const float* g2  = (const float*)d_in[8];
    const float* b2  = (const float*)d_in[9];
    const float* c1w = (const float*)d_in[10];
    const float* c1b = (const float*)d_in[11];
    const float* pa  = (const float*)d_in[12];
    const float* c2w = (const float*)d_in[13];
    const float* c2b = (const float*)d_in[14];
    const float* c3w = (const float*)d_in[15];
    const float* c3b = (const float*)d_in[16];
    const float* W1  = (const float*)d_in[17];
    const float* b1v = (const float*)d_in[18];
    const float* W2  = (const float*)d_in[19];
    const float* b2v = (const float*)d_in[20];
    float* out = (float*)d_out;
    char* ws = (char*)d_ws;

    float*          f    = (float*)(ws + 0);                 // 432,000 B
    float*          cat  = (float*)(ws + 524288);            // 6,048,000 B
    unsigned short* W1T  = (unsigned short*)(ws + 6815744);  // 256*992*2 = 507,904 B
    unsigned short* W2T  = (unsigned short*)(ws + 7340032);  // 256*8192*2 = 4,194,304 B
    unsigned short* y1   = (unsigned short*)(ws + 11534336); // 2048*8192*2 = 33,554,432 B
    float*          part = (float*)(ws + 45088768);          // 8*2048*256*4 = 16,777,216 B
    // total ~59 MB

    bert_lin<<<L_RES, 256, 0, stream>>>(beft, Wb, bb, f);
    window_attn<<<L_RES, 64, 0, stream>>>(f, g1, b1, g2, b2, cat);
    transpose_to_bf16<<<dim3(31, 8), 256, 0, stream>>>(W1, W1T, 972, 256, 992);
    transpose_to_bf16<<<dim3(256, 8), 256, 0, stream>>>(W2, W2T, 8192, 256, 8192);
    zero_pad_rows<<<768, 256, 0, stream>>>((unsigned int*)(y1 + (size_t)2000 * 8192));
    conv_mfma1<<<L_RES, 256, 0, stream>>>(cat, c1w, c1b, pa, c2w, c2b, c3w, c3b,
                                          W1T, b1v, y1);
    gemm2_mfma<<<dim3(64, 8), 256, 0, stream>>>(y1, W2T, part);
    reduce2<<<L_RES, 256, 0, stream>>>(part, b2v, out);
}